// Round 1
// baseline (318.851 us; speedup 1.0000x reference)
//
#include <hip/hip_runtime.h>
#include <cstdint>
#include <cstddef>

// Problem constants (B,C,P) = (64, 81, 8732)
#define BB 64
#define CC 81
#define PP 8732
#define CHUNKS ((PP + 255) / 256)   // 35 blocks of 256 threads per batch

// ---------------------------------------------------------------------------
// Phase 1: per-(b,p) cross-entropy loss via register-resident logsumexp.
//   con[b*P+p]  = (label>0) ? 0 : loss      (the "con_neg" array)
//   pos_sum[b] += sum of loss over positives (atomic)
//   pos_cnt[b] += count of positives         (atomic)
// ---------------------------------------------------------------------------
__global__ __launch_bounds__(256) void loss_kernel(
    const float* __restrict__ logits,   // [B, C, P]
    const int*   __restrict__ labels,   // [B, P]
    float*       __restrict__ con,      // [B, P]
    float*       __restrict__ pos_sum,  // [B]
    int*         __restrict__ pos_cnt)  // [B]
{
    const int b     = blockIdx.x / CHUNKS;
    const int chunk = blockIdx.x % CHUNKS;
    const int p     = chunk * 256 + threadIdx.x;

    float my_pos = 0.0f;
    int   my_cnt = 0;

    if (p < PP) {
        const float* base = logits + (size_t)b * CC * PP + p;
        float v[CC];
#pragma unroll
        for (int c = 0; c < CC; ++c) v[c] = base[(size_t)c * PP];

        float m = v[0];
#pragma unroll
        for (int c = 1; c < CC; ++c) m = fmaxf(m, v[c]);

        const float LOG2E = 1.4426950408889634f;
        float s = 0.0f;
#pragma unroll
        for (int c = 0; c < CC; ++c) s += exp2f((v[c] - m) * LOG2E);

        const int lab = labels[(size_t)b * PP + p];
        // dynamic index -> re-load from global (L2 hit) to keep v[] in regs
        const float x_lab = base[(size_t)lab * PP];
        const float lse   = m + 0.6931471805599453f * log2f(s);
        const float loss  = lse - x_lab;

        const bool pos = lab > 0;
        con[(size_t)b * PP + p] = pos ? 0.0f : loss;
        my_pos = pos ? loss : 0.0f;
        my_cnt = pos ? 1 : 0;
    }

    // block reduction of positive sum / count (all threads participate)
    for (int off = 32; off > 0; off >>= 1) {
        my_pos += __shfl_down(my_pos, off);
        my_cnt += __shfl_down(my_cnt, off);
    }
    __shared__ float sP[4];
    __shared__ int   sC[4];
    const int wave = threadIdx.x >> 6;
    const int lane = threadIdx.x & 63;
    if (lane == 0) { sP[wave] = my_pos; sC[wave] = my_cnt; }
    __syncthreads();
    if (threadIdx.x == 0) {
        float fp = sP[0] + sP[1] + sP[2] + sP[3];
        int   ic = sC[0] + sC[1] + sC[2] + sC[3];
        atomicAdd(&pos_sum[b], fp);
        atomicAdd(&pos_cnt[b], ic);
    }
}

// ---------------------------------------------------------------------------
// Phase 2: one block per batch. Radix-select the k-th largest con value
// (non-negative floats order like their uint bit patterns), then
//   out[b] = pos_sum[b] + sum_{v > t} v + (k - cnt_gt) * t
// which is tie-exact (boundary ties all share value t).
// ---------------------------------------------------------------------------
__global__ __launch_bounds__(256) void topk_kernel(
    const float* __restrict__ con,      // [B, P]
    const float* __restrict__ pos_sum,  // [B]
    const int*   __restrict__ pos_cnt,  // [B]
    float*       __restrict__ out)      // [B]
{
    const int b = blockIdx.x;
    __shared__ float    vals[PP];       // 34928 B
    __shared__ unsigned hist[256];
    __shared__ unsigned sb_digit, sb_k;
    __shared__ float    rs[4];
    __shared__ unsigned rc[4];

    const float* src = con + (size_t)b * PP;
    for (int i = threadIdx.x; i < PP; i += 256) vals[i] = src[i];

    const int k = min(3 * pos_cnt[b], PP);   // block-uniform
    __syncthreads();

    float result = pos_sum[b];

    if (k > 0) {
        unsigned prefix = 0;
        unsigned kk = (unsigned)k;   // rank within remaining candidate set

        for (int round = 0; round < 4; ++round) {
            const int shift = 24 - 8 * round;
            hist[threadIdx.x] = 0;   // 256 threads == 256 bins
            __syncthreads();

            const unsigned himask = (round == 0) ? 0u : (0xFFFFFFFFu << (shift + 8));
            for (int i = threadIdx.x; i < PP; i += 256) {
                const unsigned u = __float_as_uint(vals[i]);
                if ((u & himask) == prefix)
                    atomicAdd(&hist[(u >> shift) & 0xFFu], 1u);
            }
            __syncthreads();

            if (threadIdx.x == 0) {
                unsigned c = 0;
                int bin = 255;
                for (; bin > 0; --bin) {
                    const unsigned c2 = c + hist[bin];
                    if (c2 >= kk) break;
                    c = c2;
                }
                sb_digit = (unsigned)bin;
                sb_k     = kk - c;
            }
            __syncthreads();
            prefix |= sb_digit << shift;
            kk = sb_k;
            __syncthreads();   // hist reused next round
        }

        const float t = __uint_as_float(prefix);  // k-th largest value
        float    sgt = 0.0f;
        unsigned cgt = 0;
        for (int i = threadIdx.x; i < PP; i += 256) {
            const unsigned u = __float_as_uint(vals[i]);
            if (u > prefix) { sgt += vals[i]; cgt++; }
        }
        for (int off = 32; off > 0; off >>= 1) {
            sgt += __shfl_down(sgt, off);
            cgt += (unsigned)__shfl_down((int)cgt, off);
        }
        const int wave = threadIdx.x >> 6;
        const int lane = threadIdx.x & 63;
        if (lane == 0) { rs[wave] = sgt; rc[wave] = cgt; }
        __syncthreads();
        if (threadIdx.x == 0) {
            const float    S  = rs[0] + rs[1] + rs[2] + rs[3];
            const unsigned Cg = rc[0] + rc[1] + rc[2] + rc[3];
            result += S + (float)(k - (int)Cg) * t;
        }
    }

    if (threadIdx.x == 0) out[b] = result;
}

// ---------------------------------------------------------------------------
extern "C" void kernel_launch(void* const* d_in, const int* in_sizes, int n_in,
                              void* d_out, int out_size, void* d_ws, size_t ws_size,
                              hipStream_t stream) {
    // inputs: [0]=pred_loc (unused), [1]=pred_bclass [B,C,P] f32,
    //         [2]=true_loc_vec (unused), [3]=true_bclass [B,P] i32
    const float* pred_bclass = (const float*)d_in[1];
    const int*   true_bclass = (const int*)d_in[3];
    float* out = (float*)d_out;

    // workspace layout: [pos_sum: B f32][pos_cnt: B i32][con: B*P f32]
    float* pos_sum = (float*)d_ws;
    int*   pos_cnt = (int*)((char*)d_ws + BB * sizeof(float));
    float* con     = (float*)((char*)d_ws + 2 * BB * sizeof(float));

    // zero the atomic accumulators (ws is poisoned 0xAA before every launch)
    hipMemsetAsync(d_ws, 0, 2 * BB * sizeof(float), stream);

    loss_kernel<<<dim3(BB * CHUNKS), dim3(256), 0, stream>>>(
        pred_bclass, true_bclass, con, pos_sum, pos_cnt);
    topk_kernel<<<dim3(BB), dim3(256), 0, stream>>>(
        con, pos_sum, pos_cnt, out);
}